// Round 2
// baseline (62.679 us; speedup 1.0000x reference)
//
#include <hip/hip_runtime.h>

#define HH 40
#define WW 40
#define NP 36
#define NC 256
#define NB 128

// Kernel 1: per-batch offset GEMM + packed bilinear records.
// rec_w[b][p] = 4 bilinear weights; rec_i[b][p] = 4 pixel offsets in the 1600-image.
__global__ __launch_bounds__(128) void points_kernel(
    const float* __restrict__ cq, const float* __restrict__ refp,
    const float* __restrict__ Woff, const float* __restrict__ boff,
    float4* __restrict__ rec_w, int4* __restrict__ rec_i) {
    int b = blockIdx.x;
    __shared__ float4 q[NC / 4];
    __shared__ float offs[2 * NP];
    if (threadIdx.x < NC / 4)
        q[threadIdx.x] = ((const float4*)(cq + b * NC))[threadIdx.x];
    __syncthreads();
    int j = threadIdx.x;
    if (j < 2 * NP) {
        const float4* w = (const float4*)(Woff + j * NC);
        float acc = 0.f;
#pragma unroll
        for (int k = 0; k < NC / 4; ++k) {
            float4 a = q[k], bb = w[k];
            acc = fmaf(a.x, bb.x, acc);
            acc = fmaf(a.y, bb.y, acc);
            acc = fmaf(a.z, bb.z, acc);
            acc = fmaf(a.w, bb.w, acc);
        }
        offs[j] = acc + boff[j];
    }
    __syncthreads();
    int p = threadIdx.x;
    if (p < NP) {
        float sx = offs[2 * p + 0] + refp[b * 2 + 0];
        float sy = offs[2 * p + 1] + refp[b * 2 + 1];
        // grid = 2*s - 1 ; pix = ((g+1)*size - 1)/2 = s*size - 0.5 ; border clamp
        float x = fminf(fmaxf(sx * (float)WW - 0.5f, 0.f), (float)(WW - 1));
        float y = fminf(fmaxf(sy * (float)HH - 0.5f, 0.f), (float)(HH - 1));
        float x0f = floorf(x), y0f = floorf(y);
        int x0 = (int)x0f, y0 = (int)y0f;
        int x1 = min(x0 + 1, WW - 1), y1 = min(y0 + 1, HH - 1);
        float wx = x - x0f, wy = y - y0f;
        rec_w[b * NP + p] = make_float4((1.f - wx) * (1.f - wy), wx * (1.f - wy),
                                        (1.f - wx) * wy, wx * wy);
        rec_i[b * NP + p] = make_int4(y0 * WW + x0, y0 * WW + x1,
                                      y1 * WW + x0, y1 * WW + x1);
    }
}

// Kernel 2: bilinear gather for both maps. One thread per (b, 4-channel group, p).
// p varies fastest -> lanes sharing (b,c) reuse the same image lines in L1;
// record loads broadcast across the 36-lane point group.
__global__ __launch_bounds__(256) void sample_kernel(
    const float* __restrict__ fmap, const float* __restrict__ pmap,
    const float4* __restrict__ rec_w, const int4* __restrict__ rec_i,
    float* __restrict__ out) {
    int tid = blockIdx.x * 256 + threadIdx.x;
    int p = tid % NP;
    int t2 = tid / NP;
    int cq = t2 & 63;   // channel quad 0..63
    int b = t2 >> 6;    // batch 0..127

    float4 w = rec_w[b * NP + p];
    int4 io = rec_i[b * NP + p];

    long base = ((long)(b * NC) + cq * 4) * (HH * WW);
    float* o1 = out + ((long)(b * NC) + cq * 4) * NP + p;
    float* o2 = o1 + (long)NB * NC * NP;

#pragma unroll
    for (int k = 0; k < 4; ++k) {
        const float* f = fmap + base + k * (HH * WW);
        const float* g = pmap + base + k * (HH * WW);
        float vf = f[io.x] * w.x + f[io.y] * w.y + f[io.z] * w.z + f[io.w] * w.w;
        float vg = g[io.x] * w.x + g[io.y] * w.y + g[io.z] * w.z + g[io.w] * w.w;
        o1[k * NP] = vf;
        o2[k * NP] = vg;
    }
}

extern "C" void kernel_launch(void* const* d_in, const int* in_sizes, int n_in,
                              void* d_out, int out_size, void* d_ws, size_t ws_size,
                              hipStream_t stream) {
    const float* cq   = (const float*)d_in[0];  // (128, 256)
    const float* refp = (const float*)d_in[1];  // (128, 2)
    const float* fmap = (const float*)d_in[2];  // (128, 256, 1600)
    const float* pmap = (const float*)d_in[3];  // (128, 256, 1600)
    const float* Woff = (const float*)d_in[4];  // (72, 256)
    const float* boff = (const float*)d_in[5];  // (72,)
    float* out = (float*)d_out;

    float4* rec_w = (float4*)d_ws;                         // 128*36*16 B
    int4*   rec_i = (int4*)((char*)d_ws + NB * NP * 16);   // 128*36*16 B

    points_kernel<<<NB, 128, 0, stream>>>(cq, refp, Woff, boff, rec_w, rec_i);

    const int total = NB * 64 * NP;  // 294,912 threads (4 channels each)
    sample_kernel<<<total / 256, 256, 0, stream>>>(fmap, pmap, rec_w, rec_i, out);
}

// Round 3
// 51.303 us; speedup vs baseline: 1.2217x; 1.2217x over previous
//
#include <hip/hip_runtime.h>

#define HH 40
#define WW 40
#define NP 36
#define NC 256
#define NB 128

// Kernel 1: per-batch offset GEMM + packed bilinear records.
// rec_w[b][p] = 4 bilinear weights; rec_i[b][p] = 4 pixel offsets in the 1600-image.
__global__ __launch_bounds__(128) void points_kernel(
    const float* __restrict__ cq, const float* __restrict__ refp,
    const float* __restrict__ Woff, const float* __restrict__ boff,
    float4* __restrict__ rec_w, int4* __restrict__ rec_i) {
    int b = blockIdx.x;
    __shared__ float4 q[NC / 4];
    __shared__ float offs[2 * NP];
    if (threadIdx.x < NC / 4)
        q[threadIdx.x] = ((const float4*)(cq + b * NC))[threadIdx.x];
    __syncthreads();
    int j = threadIdx.x;
    if (j < 2 * NP) {
        const float4* w = (const float4*)(Woff + j * NC);
        float acc = 0.f;
#pragma unroll
        for (int k = 0; k < NC / 4; ++k) {
            float4 a = q[k], bb = w[k];
            acc = fmaf(a.x, bb.x, acc);
            acc = fmaf(a.y, bb.y, acc);
            acc = fmaf(a.z, bb.z, acc);
            acc = fmaf(a.w, bb.w, acc);
        }
        offs[j] = acc + boff[j];
    }
    __syncthreads();
    int p = threadIdx.x;
    if (p < NP) {
        float sx = offs[2 * p + 0] + refp[b * 2 + 0];
        float sy = offs[2 * p + 1] + refp[b * 2 + 1];
        // grid = 2*s - 1 ; pix = ((g+1)*size - 1)/2 = s*size - 0.5 ; border clamp
        float x = fminf(fmaxf(sx * (float)WW - 0.5f, 0.f), (float)(WW - 1));
        float y = fminf(fmaxf(sy * (float)HH - 0.5f, 0.f), (float)(HH - 1));
        float x0f = floorf(x), y0f = floorf(y);
        int x0 = (int)x0f, y0 = (int)y0f;
        int x1 = min(x0 + 1, WW - 1), y1 = min(y0 + 1, HH - 1);
        float wx = x - x0f, wy = y - y0f;
        rec_w[b * NP + p] = make_float4((1.f - wx) * (1.f - wy), wx * (1.f - wy),
                                        (1.f - wx) * wy, wx * wy);
        rec_i[b * NP + p] = make_int4(y0 * WW + x0, y0 * WW + x1,
                                      y1 * WW + x0, y1 * WW + x1);
    }
}

// Kernel 2: bilinear gather, 1 thread per (image, point).
// block = 576 threads = 16 whole images x 36 points: no image is split across
// blocks (kills duplicate cross-XCD fetch at block boundaries); p varies
// fastest so a wave's lanes share ~2 images -> L1 reuse; record loads
// broadcast across each 36-lane point group.
__global__ __launch_bounds__(576) void sample_kernel(
    const float* __restrict__ fmap, const float* __restrict__ pmap,
    const float4* __restrict__ rec_w, const int4* __restrict__ rec_i,
    float* __restrict__ out) {
    int t = threadIdx.x;            // 0..575
    int ib = t / NP;                // image-in-block 0..15
    int p = t - ib * NP;            // 0..35
    int img = blockIdx.x * 16 + ib; // 0..65535 == b*256 + c
    int b = img >> 8;

    float4 w = rec_w[b * NP + p];
    int4 io = rec_i[b * NP + p];

    long base = (long)img * (HH * WW);
    const float* f = fmap + base;
    const float* g = pmap + base;

    float vf = f[io.x] * w.x + f[io.y] * w.y + f[io.z] * w.z + f[io.w] * w.w;
    float vg = g[io.x] * w.x + g[io.y] * w.y + g[io.z] * w.z + g[io.w] * w.w;

    long oidx = (long)img * NP + p;
    out[oidx] = vf;
    out[(long)NB * NC * NP + oidx] = vg;
}

extern "C" void kernel_launch(void* const* d_in, const int* in_sizes, int n_in,
                              void* d_out, int out_size, void* d_ws, size_t ws_size,
                              hipStream_t stream) {
    const float* cq   = (const float*)d_in[0];  // (128, 256)
    const float* refp = (const float*)d_in[1];  // (128, 2)
    const float* fmap = (const float*)d_in[2];  // (128, 256, 1600)
    const float* pmap = (const float*)d_in[3];  // (128, 256, 1600)
    const float* Woff = (const float*)d_in[4];  // (72, 256)
    const float* boff = (const float*)d_in[5];  // (72,)
    float* out = (float*)d_out;

    float4* rec_w = (float4*)d_ws;                         // 128*36*16 B
    int4*   rec_i = (int4*)((char*)d_ws + NB * NP * 16);   // 128*36*16 B

    points_kernel<<<NB, 128, 0, stream>>>(cq, refp, Woff, boff, rec_w, rec_i);

    // 65536 images / 16 per block = 4096 blocks of 576 threads.
    sample_kernel<<<(NB * NC) / 16, 576, 0, stream>>>(fmap, pmap, rec_w, rec_i, out);
}